// Round 5
// baseline (306.416 us; speedup 1.0000x reference)
//
#include <hip/hip_runtime.h>
#include <cstdint>

// GraphormerMultiHeadAttention on MI355X (gfx950), bf16 MFMA path.
// B=16, N=512, D=1024, H=16, hd=64. scale = D^-0.5 = 1/32.
//
// R6 -> R7: qkv/oproj ported from the 2-barrier 128x128 structure (~740 TF,
// structural ceiling ~900) to a deep-pipelined 256x128 schedule (T3+T4+T5):
//  - 512 threads / 8 waves (4M x 2N), per-wave 64x64 output, acc[4][4].
//  - LDS 128 KiB: A triple-buffered (3 x 32KB), B double-buffered (2 x 16KB).
//  - 4 phases per K-step: {issue 2 global_load_lds; ds_read frags; barrier;
//    setprio(1); 8 MFMA; setprio(0); barrier}. Loads are never drained to 0
//    mid-loop: end-of-iter s_waitcnt vmcnt(4) retires exactly A[t+1]+B[t+1]
//    (the 6 oldest), keeping A[t+2] (4 loads) in flight across the barrier.
//  - Ledger: iter t issues B[t+1] in ph0, A[t+2] in ph1/ph2. A-prefetch has a
//    2-K-step latency budget (~800cy); B (L2-hot weights) 1 step.
//  - Race-freedom: buffer written at iter t was last READ at iter t-1; every
//    ds_read is serviced before its phase's MFMA, which precedes the end
//    barrier. Same XOR swizzle staging/read pair as the verified 128x128 core.
// attn + casts byte-identical to R6 (passed).

typedef unsigned short u16;
typedef unsigned int   u32;
typedef __attribute__((ext_vector_type(8))) short bf8;   // 8 x bf16 (4 VGPRs)
typedef __attribute__((ext_vector_type(4))) float f4;    // 4 x f32 accum

__device__ __forceinline__ u16 f2bf(float x) {
  u32 u = __float_as_uint(x);
  u += 0x7FFF + ((u >> 16) & 1);        // round-to-nearest-even
  return (u16)(u >> 16);
}

__device__ __forceinline__ float bf2f(u16 x) {
  return __uint_as_float(((u32)x) << 16);
}

// async global->LDS, 16B per lane. LDS dest = wave-uniform base + lane*16.
__device__ __forceinline__ void gl2lds16(const void* g, void* l) {
  __builtin_amdgcn_global_load_lds(
      (const __attribute__((address_space(1))) u32*)g,
      (__attribute__((address_space(3))) u32*)l, 16, 0, 0);
}

// raw workgroup barrier WITHOUT the __syncthreads vmcnt(0) drain.
__device__ __forceinline__ void barrier_raw() {
  asm volatile("" ::: "memory");
  __builtin_amdgcn_s_barrier();
  asm volatile("" ::: "memory");
}

// ---------------- cast kernels ----------------

__global__ __launch_bounds__(256) void cast_bf16(const float* __restrict__ src,
                                                 uint4* __restrict__ dst, int n8) {
  const int i = blockIdx.x * 256 + threadIdx.x;
  if (i >= n8) return;
  const float4* s = (const float4*)src;
  const float4 a = s[2 * i], c = s[2 * i + 1];
  uint4 o;
  o.x = (u32)f2bf(a.x) | ((u32)f2bf(a.y) << 16);
  o.y = (u32)f2bf(a.z) | ((u32)f2bf(a.w) << 16);
  o.z = (u32)f2bf(c.x) | ((u32)f2bf(c.y) << 16);
  o.w = (u32)f2bf(c.z) | ((u32)f2bf(c.w) << 16);
  dst[i] = o;
}

// 4 weight matrices (1M elems each) in one launch: i>>17 selects the matrix.
__global__ __launch_bounds__(256) void cast4_bf16(
    const float* __restrict__ s0, const float* __restrict__ s1,
    const float* __restrict__ s2, const float* __restrict__ s3,
    uint4* __restrict__ d0, uint4* __restrict__ d1,
    uint4* __restrict__ d2, uint4* __restrict__ d3) {
  const int i = blockIdx.x * 256 + threadIdx.x;     // 0 .. 524287
  const int w = i >> 17, j = i & 131071;
  const float* src = (w == 0) ? s0 : (w == 1) ? s1 : (w == 2) ? s2 : s3;
  uint4* dst = (w == 0) ? d0 : (w == 1) ? d1 : (w == 2) ? d2 : d3;
  const float4* s = (const float4*)src;
  const float4 a = s[2 * j], c = s[2 * j + 1];
  uint4 o;
  o.x = (u32)f2bf(a.x) | ((u32)f2bf(a.y) << 16);
  o.y = (u32)f2bf(a.z) | ((u32)f2bf(a.w) << 16);
  o.z = (u32)f2bf(c.x) | ((u32)f2bf(c.y) << 16);
  o.w = (u32)f2bf(c.z) | ((u32)f2bf(c.w) << 16);
  dst[j] = o;
}

// bias = bf16(sp+ed), permuted so attn lane `tid` of block (b, qt, jt) reads
// its 16 values (4 rows x 4 col-groups) as one contiguous 32B chunk.
__global__ __launch_bounds__(256) void bias_perm(const float* __restrict__ sp,
                                                 const float* __restrict__ ed,
                                                 u16* __restrict__ Bp) {
  const int jt = blockIdx.x, qt = blockIdx.y, b = blockIdx.z;
  const int tid = threadIdx.x;
  const int wave = tid >> 6, quad = (tid >> 4) & 3, l16 = tid & 15;
  const int qrl = (wave << 4) + (quad << 2);
  union { u16 a[16]; uint4 v[2]; } tmp;
#pragma unroll
  for (int nb = 0; nb < 4; nb++) {
    const int col = (jt << 6) + (nb << 4) + l16;
#pragma unroll
    for (int r = 0; r < 4; r++) {
      const int row = (qt << 6) + qrl + r;
      const size_t idx = ((size_t)b << 18) + (size_t)row * 512 + col;
      tmp.a[nb * 4 + r] = f2bf(sp[idx] + ed[idx]);
    }
  }
  uint4* out = (uint4*)Bp + ((((size_t)b * 8 + qt) * 8 + jt) * 256 + tid) * 2;
  out[0] = tmp.v[0];
  out[1] = tmp.v[1];
}

// ---------------- deep-pipelined GEMM core ----------------
// C(256x128) = A(256x1024) . Bt(128x1024)^T, 512 threads, 8 waves (4M x 2N).
// LDS tiles [rows][8 chunks of 16B]; slot (r,c) holds global chunk c^(r&7).
// SWAP=true computes C^T fragments (mfma(B,A)): l16 -> M, (quad,reg) -> N.

#define RA(mi, off) (*(const bf8*)(lA + (wm + ((mi) << 4) + l16) * 64 + (off)))
#define RB(ni, off) (*(const bf8*)(lB + (wn + ((ni) << 4) + l16) * 64 + (off)))

template <bool SWAP>
__device__ __forceinline__ void gemm_8ph(const u16* __restrict__ A,
                                         const u16* __restrict__ Bt,
                                         int m0, int n0,
                                         u16* sA, u16* sB, f4 acc[4][4]) {
  const int tid  = threadIdx.x;
  const int wave = tid >> 6;              // 0..7
  const int lane = tid & 63;
  const int quad = lane >> 4;
  const int l16  = lane & 15;
  const int wm   = (wave & 3) << 6;       // 0,64,128,192
  const int wn   = (wave >> 2) << 6;      // 0,64
  const int srow = tid >> 3;              // 0..63
  const int scol = ((tid & 7) ^ (srow & 7)) << 3;   // swizzled source chunk
  const int c0   = (quad ^ (l16 & 7)) << 3;         // swizzled read offset

  f4 zero = {0.f, 0.f, 0.f, 0.f};
#pragma unroll
  for (int mi = 0; mi < 4; mi++)
#pragma unroll
    for (int ni = 0; ni < 4; ni++) acc[mi][ni] = zero;

  const u16* Ab = A  + (size_t)(m0 + srow) * 1024 + scol;
  const u16* Bb = Bt + (size_t)(n0 + srow) * 1024 + scol;
  const int ldsbase = (wave << 6) << 4;   // per-wave byte base within a call

  // ---- prologue: A[0] (4 loads), B[0] (2), A[1] (4); retire A0+B0 ----
#pragma unroll
  for (int i = 0; i < 4; i++)
    gl2lds16(Ab + (size_t)(i << 6) * 1024,
             (char*)sA + ((i << 9) << 4) + ldsbase);
#pragma unroll
  for (int i = 0; i < 2; i++)
    gl2lds16(Bb + (size_t)(i << 6) * 1024,
             (char*)sB + ((i << 9) << 4) + ldsbase);
#pragma unroll
  for (int i = 0; i < 4; i++)
    gl2lds16(Ab + (size_t)(i << 6) * 1024 + 64,
             (char*)(sA + 16384) + ((i << 9) << 4) + ldsbase);
  asm volatile("s_waitcnt vmcnt(4)" ::: "memory");
  barrier_raw();

  int a_cur = 0, a_nxt = 2;               // A buf of tile t / tile t+2
  for (int t = 0; t < 16; t++) {
    const u16* lA = sA + a_cur * 16384;
    const u16* lB = sB + (t & 1) * 8192;
    char* nA = (char*)(sA + a_nxt * 16384);
    char* nB = (char*)(sB + ((t + 1) & 1) * 8192);
    const int kA = (t + 2) << 6;
    const int kB = (t + 1) << 6;

    bf8 bF0, bF1, bF2, bF3;

    // ---- phase 0: ksub0, mi{0,1}; issue B[t+1] ----
    if (t <= 14) {
#pragma unroll
      for (int i = 0; i < 2; i++)
        gl2lds16(Bb + (size_t)(i << 6) * 1024 + kB,
                 nB + ((i << 9) << 4) + ldsbase);
    }
    bF0 = RB(0, c0); bF1 = RB(1, c0); bF2 = RB(2, c0); bF3 = RB(3, c0);
    {
      bf8 a0 = RA(0, c0), a1 = RA(1, c0);
      barrier_raw();
      __builtin_amdgcn_s_setprio(1);
      if (SWAP) {
        acc[0][0] = __builtin_amdgcn_mfma_f32_16x16x32_bf16(bF0, a0, acc[0][0], 0, 0, 0);
        acc[0][1] = __builtin_amdgcn_mfma_f32_16x16x32_bf16(bF1, a0, acc[0][1], 0, 0, 0);
        acc[0][2] = __builtin_amdgcn_mfma_f32_16x16x32_bf16(bF2, a0, acc[0][2], 0, 0, 0);
        acc[0][3] = __builtin_amdgcn_mfma_f32_16x16x32_bf16(bF3, a0, acc[0][3], 0, 0, 0);
        acc[1][0] = __builtin_amdgcn_mfma_f32_16x16x32_bf16(bF0, a1, acc[1][0], 0, 0, 0);
        acc[1][1] = __builtin_amdgcn_mfma_f32_16x16x32_bf16(bF1, a1, acc[1][1], 0, 0, 0);
        acc[1][2] = __builtin_amdgcn_mfma_f32_16x16x32_bf16(bF2, a1, acc[1][2], 0, 0, 0);
        acc[1][3] = __builtin_amdgcn_mfma_f32_16x16x32_bf16(bF3, a1, acc[1][3], 0, 0, 0);
      } else {
        acc[0][0] = __builtin_amdgcn_mfma_f32_16x16x32_bf16(a0, bF0, acc[0][0], 0, 0, 0);
        acc[0][1] = __builtin_amdgcn_mfma_f32_16x16x32_bf16(a0, bF1, acc[0][1], 0, 0, 0);
        acc[0][2] = __builtin_amdgcn_mfma_f32_16x16x32_bf16(a0, bF2, acc[0][2], 0, 0, 0);
        acc[0][3] = __builtin_amdgcn_mfma_f32_16x16x32_bf16(a0, bF3, acc[0][3], 0, 0, 0);
        acc[1][0] = __builtin_amdgcn_mfma_f32_16x16x32_bf16(a1, bF0, acc[1][0], 0, 0, 0);
        acc[1][1] = __builtin_amdgcn_mfma_f32_16x16x32_bf16(a1, bF1, acc[1][1], 0, 0, 0);
        acc[1][2] = __builtin_amdgcn_mfma_f32_16x16x32_bf16(a1, bF2, acc[1][2], 0, 0, 0);
        acc[1][3] = __builtin_amdgcn_mfma_f32_16x16x32_bf16(a1, bF3, acc[1][3], 0, 0, 0);
      }
      __builtin_amdgcn_s_setprio(0);
      barrier_raw();
    }

    // ---- phase 1: ksub0, mi{2,3}; issue A[t+2] rows 0-127 ----
    if (t <= 13) {
#pragma unroll
      for (int i = 0; i < 2; i++)
        gl2lds16(Ab + (size_t)(i << 6) * 1024 + kA,
                 nA + ((i << 9) << 4) + ldsbase);
    }
    {
      bf8 a2 = RA(2, c0), a3 = RA(3, c0);
      barrier_raw();
      __builtin_amdgcn_s_setprio(1);
      if (SWAP) {
        acc[2][0] = __builtin_amdgcn_mfma_f32_16x16x32_bf16(bF0, a2, acc[2][0], 0, 0, 0);
        acc[2][1] = __builtin_amdgcn_mfma_f32_16x16x32_bf16(bF1, a2, acc[2][1], 0, 0, 0);
        acc[2][2] = __builtin_amdgcn_mfma_f32_16x16x32_bf16(bF2, a2, acc[2][2], 0, 0, 0);
        acc[2][3] = __builtin_amdgcn_mfma_f32_16x16x32_bf16(bF3, a2, acc[2][3], 0, 0, 0);
        acc[3][0] = __builtin_amdgcn_mfma_f32_16x16x32_bf16(bF0, a3, acc[3][0], 0, 0, 0);
        acc[3][1] = __builtin_amdgcn_mfma_f32_16x16x32_bf16(bF1, a3, acc[3][1], 0, 0, 0);
        acc[3][2] = __builtin_amdgcn_mfma_f32_16x16x32_bf16(bF2, a3, acc[3][2], 0, 0, 0);
        acc[3][3] = __builtin_amdgcn_mfma_f32_16x16x32_bf16(bF3, a3, acc[3][3], 0, 0, 0);
      } else {
        acc[2][0] = __builtin_amdgcn_mfma_f32_16x16x32_bf16(a2, bF0, acc[2][0], 0, 0, 0);
        acc[2][1] = __builtin_amdgcn_mfma_f32_16x16x32_bf16(a2, bF1, acc[2][1], 0, 0, 0);
        acc[2][2] = __builtin_amdgcn_mfma_f32_16x16x32_bf16(a2, bF2, acc[2][2], 0, 0, 0);
        acc[2][3] = __builtin_amdgcn_mfma_f32_16x16x32_bf16(a2, bF3, acc[2][3], 0, 0, 0);
        acc[3][0] = __builtin_amdgcn_mfma_f32_16x16x32_bf16(a3, bF0, acc[3][0], 0, 0, 0);
        acc[3][1] = __builtin_amdgcn_mfma_f32_16x16x32_bf16(a3, bF1, acc[3][1], 0, 0, 0);
        acc[3][2] = __builtin_amdgcn_mfma_f32_16x16x32_bf16(a3, bF2, acc[3][2], 0, 0, 0);
        acc[3][3] = __builtin_amdgcn_mfma_f32_16x16x32_bf16(a3, bF3, acc[3][3], 0, 0, 0);
      }
      __builtin_amdgcn_s_setprio(0);
      barrier_raw();
    }

    // ---- phase 2: ksub1, mi{0,1}; issue A[t+2] rows 128-255 ----
    if (t <= 13) {
#pragma unroll
      for (int i = 2; i < 4; i++)
        gl2lds16(Ab + (size_t)(i << 6) * 1024 + kA,
                 nA + ((i << 9) << 4) + ldsbase);
    }
    const int c1 = c0 ^ 32;
    bF0 = RB(0, c1); bF1 = RB(1, c1); bF2 = RB(2, c1); bF3 = RB(3, c1);
    {
      bf8 a0 = RA(0, c1), a1 = RA(1, c1);
      barrier_raw();
      __builtin_amdgcn_s_setprio(1);
      if (SWAP) {
        acc[0][0] = __builtin_amdgcn_mfma_f32_16x16x32_bf16(bF0, a0, acc[0][0], 0, 0, 0);
        acc[0][1] = __builtin_amdgcn_mfma_f32_16x16x32_bf16(bF1, a0, acc[0][1], 0, 0, 0);
        acc[0][2] = __builtin_amdgcn_mfma_f32_16x16x32_bf16(bF2, a0, acc[0][2], 0, 0, 0);
        acc[0][3] = __builtin_amdgcn_mfma_f32_16x16x32_bf16(bF3, a0, acc[0][3], 0, 0, 0);
        acc[1][0] = __builtin_amdgcn_mfma_f32_16x16x32_bf16(bF0, a1, acc[1][0], 0, 0, 0);
        acc[1][1] = __builtin_amdgcn_mfma_f32_16x16x32_bf16(bF1, a1, acc[1][1], 0, 0, 0);
        acc[1][2] = __builtin_amdgcn_mfma_f32_16x16x32_bf16(bF2, a1, acc[1][2], 0, 0, 0);
        acc[1][3] = __builtin_amdgcn_mfma_f32_16x16x32_bf16(bF3, a1, acc[1][3], 0, 0, 0);
      } else {
        acc[0][0] = __builtin_amdgcn_mfma_f32_16x16x32_bf16(a0, bF0, acc[0][0], 0, 0, 0);
        acc[0][1] = __builtin_amdgcn_mfma_f32_16x16x32_bf16(a0, bF1, acc[0][1], 0, 0, 0);
        acc[0][2] = __builtin_amdgcn_mfma_f32_16x16x32_bf16(a0, bF2, acc[0][2], 0, 0, 0);
        acc[0][3] = __builtin_amdgcn_mfma_f32_16x16x32_bf16(a0, bF3, acc[0][3], 0, 0, 0);
        acc[1][0] = __builtin_amdgcn_mfma_f32_16x16x32_bf16(a1, bF0, acc[1][0], 0, 0, 0);
        acc[1][1] = __builtin_amdgcn_mfma_f32_16x16x32_bf16(a1, bF1, acc[1][1], 0, 0, 0);
        acc[1][2] = __builtin_amdgcn_mfma_f32_16x16x32_bf16(a1, bF2, acc[1][2], 0, 0, 0);
        acc[1][3] = __builtin_amdgcn_mfma_f32_16x16x32_bf16(a1, bF3, acc[1][3], 0, 0, 0);
      }
      __builtin_amdgcn_s_setprio(0);
      barrier_raw();
    }

    // ---- phase 3: ksub1, mi{2,3}; end-of-iter counted wait ----
    {
      bf8 a2 = RA(2, c1), a3 = RA(3, c1);
      barrier_raw();
      __builtin_amdgcn_s_setprio(1);
      if (SWAP) {
        acc[2][0] = __builtin_amdgcn_mfma_f32_16x16x32_bf16(bF0, a2, acc[2][0], 0, 0, 0);
        acc[2][1] = __builtin_amdgcn_mfma_f32_16x16x32_bf16(bF1, a2, acc[2][1], 0, 0, 0);
        acc[2][2] = __builtin_amdgcn_mfma_f32_16x16x32_bf16(bF2, a2, acc[2][2], 0, 0, 0);
        acc[2][3] = __builtin_amdgcn_mfma_f32_16x16x32_bf16(bF3, a2, acc[2][3], 0, 0, 0);
        acc[3][0] = __builtin_amdgcn_mfma_f32_16x16x32_bf16(bF0, a3, acc[3][0], 0, 0, 0);
        acc[3][1] = __builtin_amdgcn_mfma_f32_16x16x32_bf16(bF1, a3, acc[3][1], 0, 0, 0);
        acc[3][2] = __builtin_amdgcn_mfma_f32_16x16x32_bf16(bF2, a3, acc[3][2], 0, 0, 0);
        acc[3][3] = __builtin_amdgcn_mfma_f32_16x16x32_bf16(bF3, a3, acc[3][3], 0, 0, 0);
      } else {
        acc[2][0] = __builtin_amdgcn_mfma_f32_16x16x32_bf16(a2, bF0, acc[2][0], 0, 0, 0);
        acc[2][1] = __builtin_amdgcn_mfma_f32_16x16x32_bf16(a2, bF1, acc[2][1], 0, 0, 0);
        acc[2][2] = __builtin_amdgcn_mfma_f32_16x16x32_bf16(a2, bF2, acc[2][2], 0, 0, 0);
        acc[2][3] = __builtin_amdgcn_mfma_f32_16x16x32_bf16(a2, bF3, acc[2][3], 0, 0, 0);
        acc[3][0] = __builtin_amdgcn_mfma_f32_16x16x32_bf16(a3, bF0, acc[3][0], 0, 0, 0);
        acc[3][1] = __builtin_amdgcn_mfma_f32_16x16x32_bf16(a3, bF1, acc[3][1], 0, 0, 0);
        acc[3][2] = __builtin_amdgcn_mfma_f32_16x16x32_bf16(a3, bF2, acc[3][2], 0, 0, 0);
        acc[3][3] = __builtin_amdgcn_mfma_f32_16x16x32_bf16(a3, bF3, acc[3][3], 0, 0, 0);
      }
      __builtin_amdgcn_s_setprio(0);
    }
    if (t <= 13)
      asm volatile("s_waitcnt vmcnt(4)" ::: "memory");   // A[t+1]+B[t+1] landed
    else if (t == 14)
      asm volatile("s_waitcnt vmcnt(0)" ::: "memory");   // A[15]+B[15] landed
    barrier_raw();

    a_cur = (a_cur == 2) ? 0 : a_cur + 1;
    a_nxt = (a_nxt == 2) ? 0 : a_nxt + 1;
  }
}

#undef RA
#undef RB

// ---------------- QKV projection ----------------
// 768 wgs: flat bits [2:0]=m_lo(XCD) [5:3]=n_tile [7:6]=m_hi [9:8]=proj.
// Round 1 of 256 wgs = proj 0 only: per-XCD L2 set = 4 A-slices (2MB) + Wq (2MB).

__global__ __launch_bounds__(512, 2) void qkv_kernel(
    const u16* __restrict__ xb, const u16* __restrict__ wq,
    const u16* __restrict__ wk, const u16* __restrict__ wv,
    u16* __restrict__ Qh, u16* __restrict__ Kh, u16* __restrict__ Vt) {
  __shared__ __align__(16) u16 sA[3 * 16384];   // 96 KB
  __shared__ __align__(16) u16 sB[2 * 8192];    // 32 KB
  const int flat = blockIdx.x + (blockIdx.y << 3) + (blockIdx.z << 6);
  const int m_tile = (flat & 7) | (((flat >> 6) & 3) << 3);   // 0..31
  const int n_tile = (flat >> 3) & 7;                          // 0..7
  const int proj = flat >> 8;                                  // 0..2
  const int m0 = m_tile << 8, n0 = n_tile << 7;
  const u16* W = (proj == 0) ? wq : (proj == 1) ? wk : wv;

  const int tid = threadIdx.x, wave = tid >> 6, lane = tid & 63;
  const int quad = lane >> 4, l16 = lane & 15;
  const int wm = (wave & 3) << 6, wn = (wave >> 2) << 6;
  f4 acc[4][4];

  if (proj == 2) {
    // V: normal orientation; (quad,reg) = tokens = contiguous dim of Vt.
    gemm_8ph<false>(xb, W, m0, n0, sA, sB, acc);
#pragma unroll
    for (int mi = 0; mi < 4; mi++) {
      const int gmb = m0 + wm + (mi << 4) + (quad << 2);
      const int b = gmb >> 9, nb = gmb & 511;
#pragma unroll
      for (int ni = 0; ni < 4; ni++) {
        const int gn = n0 + wn + (ni << 4) + l16;
        const int h = gn >> 6, hdi = gn & 63;
        ushort4 pk;
        pk.x = f2bf(acc[mi][ni][0]);
        pk.y = f2bf(acc[mi][ni][1]);
        pk.z = f2bf(acc[mi][ni][2]);
        pk.w = f2bf(acc[mi][ni][3]);
        *(ushort4*)(Vt + ((size_t)((b << 4) + h) * 64 + hdi) * 512 + nb) = pk;
      }
    }
  } else {
    // Q/K: transposed fragments; (quad,reg) = hd (contiguous), l16 = token.
    gemm_8ph<true>(xb, W, m0, n0, sA, sB, acc);
    u16* dst = (proj == 0) ? Qh : Kh;
#pragma unroll
    for (int mi = 0; mi < 4; mi++) {
      const int gm = m0 + wm + (mi << 4) + l16;
      const int b = gm >> 9, n = gm & 511;
#pragma unroll
      for (int ni = 0; ni < 4; ni++) {
        const int gn = n0 + wn + (ni << 4) + (quad << 2);
        const int h = gn >> 6, hdi = gn & 63;
        ushort4 pk;
        pk.x = f2bf(acc[mi][ni][0]);
        pk.y = f2bf(acc[mi][ni][1]);
        pk.z = f2bf(acc[mi][ni][2]);
        pk.w = f2bf(acc[mi][ni][3]);
        *(ushort4*)(dst + ((size_t)((b << 4) + h) * 512 + n) * 64 + hdi) = pk;
      }
    }
  }
}

// ---------------- output projection ----------------
// 256 wgs: flat bits [2:0]=m_lo [5:3]=n_tile [7:6]=m_hi.

__global__ __launch_bounds__(512, 2) void oproj_kernel(const u16* __restrict__ Ob,
                                                       const u16* __restrict__ wo,
                                                       float* __restrict__ out) {
  __shared__ __align__(16) u16 sA[3 * 16384];
  __shared__ __align__(16) u16 sB[2 * 8192];
  const int flat = blockIdx.x + (blockIdx.y << 3) + (blockIdx.z << 6);
  const int m0 = ((flat & 7) | (((flat >> 6) & 3) << 3)) << 8;
  const int n0 = ((flat >> 3) & 7) << 7;
  f4 acc[4][4];
  gemm_8ph<true>(Ob, wo, m0, n0, sA, sB, acc);

  const int tid = threadIdx.x, wave = tid >> 6, lane = tid & 63;
  const int quad = lane >> 4, l16 = lane & 15;
  const int wm = (wave & 3) << 6, wn = (wave >> 2) << 6;
#pragma unroll
  for (int mi = 0; mi < 4; mi++) {
    const int gm = m0 + wm + (mi << 4) + l16;
#pragma unroll
    for (int ni = 0; ni < 4; ni++) {
      const int gn = n0 + wn + (ni << 4) + (quad << 2);
      float4 f;
      f.x = acc[mi][ni][0];
      f.y = acc[mi][ni][1];
      f.z = acc[mi][ni][2];
      f.w = acc[mi][ni][3];
      *(float4*)(out + (size_t)gm * 1024 + gn) = f;
    }
  }
}

// ---------------- fused attention (R6, unchanged) ----------------

__global__ __launch_bounds__(256, 5) void attn_kernel(
    const u16* __restrict__ Qh, const u16* __restrict__ Kh,
    const u16* __restrict__ Vt, const u16* __restrict__ Bp,
    u16* __restrict__ Ob) {
  __shared__ __align__(16) u16 sK[64 * 64];
  __shared__ __align__(16) u16 sV[64 * 64];        // [hd][j] layout
  __shared__ __align__(16) u16 sP[4 * 16 * 72];    // stride 72 (pad vs bank conflicts)
  const int flat = blockIdx.x + (blockIdx.y << 3) + (blockIdx.z << 7);
  const int qt = (flat >> 3) & 7;
  const int h  = (flat >> 6) & 15;
  const int b  = (flat & 7) | (((flat >> 10) & 1) << 3);
  const int q0 = qt << 6;
  const int tid = threadIdx.x, wave = tid >> 6, lane = tid & 63;
  const int quad = lane >> 4, l16 = lane & 15;
  const int c0  = (quad ^ (l16 & 7)) << 3;
  const int swb = (((tid & 7) ^ ((tid >> 3) & 7)) << 4);

  const u16* Qg = Qh + ((size_t)((b << 4) + h) * 512 + q0) * 64;
  const u16* Kg = Kh + (size_t)((b << 4) + h) * 512 * 64;
  const u16* Vg = Vt + (size_t)((b << 4) + h) * 64 * 512;
  const uint4* Bpg = (const uint4*)Bp + (((size_t)b * 8 + qt) * 8 * 256 + tid) * 2;

  const bf8 aq0 = *(const bf8*)(Qg + ((wave << 4) + l16) * 64 + (quad << 3));
  const bf8 aq1 = *(const bf8*)(Qg + ((wave << 4) + l16) * 64 + 32 + (quad << 3));

  f4 o[4];
  f4 zero = {0.f, 0.f, 0.f, 0.f};
#pragma unroll
  for (int i = 0; i < 4; i++) o[i] = zero;
  float lsum[4] = {0.f, 0.f, 0.f, 0.f};
  const int qrl = (wave << 4) + (quad << 2);

  for (int j0 = 0; j0 < 512; j0 += 64) {
    const uint4 bc0 = Bpg[(j0 >> 6) * 512];
    const uint4 bc1 = Bpg[(j0 >> 6) * 512 + 1];
    const u32 bw[8] = {bc0.x, bc0.y, bc0.z, bc0.w, bc1.x, bc1.y, bc1.z, bc1.w};

    __syncthreads();
#pragma unroll
    for (int i = 0; i < 2; i++) {
      const int e = (i << 8) + tid;
      gl2lds16((const char*)Kg + (size_t)j0 * 128 + (e >> 3) * 128 + swb,
               (char*)sK + (((i << 8) + (wave << 6)) << 4));
      gl2lds16((const char*)Vg + (size_t)(e >> 3) * 1024 + j0 * 2 + swb,
               (char*)sV + (((i << 8) + (wave << 6)) << 4));
    }
    __syncthreads();

    u16* pw = sP + wave * (16 * 72);
#pragma unroll
    for (int nb = 0; nb < 4; nb++) {
      bf8 b0 = *(const bf8*)(sK + ((nb << 4) + l16) * 64 + c0);
      bf8 b1 = *(const bf8*)(sK + ((nb << 4) + l16) * 64 + (c0 ^ 32));
      f4 s = zero;
      s = __builtin_amdgcn_mfma_f32_16x16x32_bf16(aq0, b0, s, 0, 0, 0);
      s = __builtin_amdgcn_mfma_f32_16x16x32_bf16(aq1, b1, s, 0, 0, 0);
#pragma unroll
      for (int r = 0; r < 4; r++) {
        const u32 w = bw[nb * 2 + (r >> 1)];
        const float bias = bf2f((r & 1) ? (u16)(w >> 16) : (u16)(w & 0xFFFF));
        const float ev = __expf(s[r] * 0.03125f + bias);
        lsum[r] += ev;
        pw[((quad << 2) + r) * 72 + (nb << 4) + l16] = f2bf(ev);
      }
    }

    bf8 ap0 = *(const bf8*)(pw + l16 * 72 + (quad << 3));
    bf8 ap1 = *(const bf8*)(pw + l16 * 72 + 32 + (quad << 3));
#pragma unroll
    for (int db = 0; db < 4; db++) {
      bf8 v0 = *(const bf8*)(sV + ((db << 4) + l16) * 64 + c0);
      bf8 v1 = *(const bf8*)(sV + ((db << 4) + l16) * 64 + (c0 ^ 32));
      o[db] = __builtin_amdgcn_mfma_f32_16x16x32_bf16(ap0, v0, o[db], 0, 0, 0);
      o[db] = __builtin_amdgcn_mfma_f32_16x16x32_bf16(ap1, v1, o[db], 0, 0, 0);
    }
  }

#pragma unroll
  for (int r = 0; r < 4; r++) {
    float s = lsum[r];
    s += __shfl_xor(s, 1);
    s += __shfl_xor(s, 2);
    s += __shfl_xor(s, 4);
    s += __shfl_xor(s, 8);
    const float inv = 1.f / s;
    const int gr = q0 + qrl + r;
#pragma unroll
    for (int db = 0; db < 4; db++)
      Ob[(size_t)((b << 9) + gr) * 1024 + (h << 6) + (db << 4) + l16] =
          f2bf(o[db][r] * inv);
  }
}

// ---------------- launch ----------------

extern "C" void kernel_launch(void* const* d_in, const int* in_sizes, int n_in,
                              void* d_out, int out_size, void* d_ws, size_t ws_size,
                              hipStream_t stream) {
  const float* x  = (const float*)d_in[0];
  const float* sp = (const float*)d_in[1];
  const float* ed = (const float*)d_in[2];
  const float* Wq = (const float*)d_in[3];
  const float* Wk = (const float*)d_in[4];
  const float* Wv = (const float*)d_in[5];
  const float* Wo = (const float*)d_in[6];
  float* out = (float*)d_out;

  char* w = (char*)d_ws;
  u16* xb  = (u16*)(w);                  // 16 MB  : x bf16 [8192][1024]
  u16* wqb = (u16*)(w + 16777216);       // 2 MB
  u16* wkb = (u16*)(w + 18874368);
  u16* wvb = (u16*)(w + 20971520);
  u16* wob = (u16*)(w + 23068672);
  u16* Qh  = (u16*)(w + 25165824);       // 16 MB  : [B,H,512,64]
  u16* Kh  = (u16*)(w + 41943040);       // 16 MB
  u16* Vt  = (u16*)(w + 58720256);       // 16 MB  : [B,H,64,512]
  u16* Ob  = (u16*)(w + 75497472);       // 16 MB  : [8192][1024]
  u16* Bp  = (u16*)(w + 92274688);       // 8 MB   : permuted bf16(sp+ed)

  cast_bf16<<<4096, 256, 0, stream>>>(x, (uint4*)xb, 1048576);
  cast4_bf16<<<2048, 256, 0, stream>>>(Wq, Wk, Wv, Wo,
                                       (uint4*)wqb, (uint4*)wkb,
                                       (uint4*)wvb, (uint4*)wob);
  bias_perm<<<dim3(8, 8, 16), 256, 0, stream>>>(sp, ed, Bp);

  qkv_kernel<<<dim3(8, 8, 12), 512, 0, stream>>>(xb, wqb, wkb, wvb, Qh, Kh, Vt);
  attn_kernel<<<dim3(8, 16, 16), 256, 0, stream>>>(Qh, Kh, Vt, Bp, Ob);
  oproj_kernel<<<dim3(8, 8, 4), 512, 0, stream>>>(Ob, wob, out);
}

// Round 6
// 257.315 us; speedup vs baseline: 1.1908x; 1.1908x over previous
//
#include <hip/hip_runtime.h>
#include <cstdint>

// GraphormerMultiHeadAttention on MI355X (gfx950), bf16 MFMA path.
// B=16, N=512, D=1024, H=16, hd=64. scale = D^-0.5 = 1/32.
//
// R7 -> R8:
//  - qkv/oproj REVERTED to the proven 2-barrier 128x128 gemm_core (R6: 69.4us
//    qkv, MfmaUtil 30%). The R7 deep-pipeline port measured 108us / MfmaUtil
//    18%: 128KB LDS -> 1 block/CU, 8 barriers/K-step with only 8 MFMA between
//    them, no co-resident block to hide latency. Plateau accepted.
//  - attn: QBLK 64 -> 128 (512 threads, 8 waves). Each staged K/V tile now
//    feeds 128 q-rows: staging traffic + gl2lds count halve (K/V 256->128MB),
//    2 loads per drain instead of 4. Per-wave work unchanged. LDS 34.8KB,
//    2 blocks/CU (16 waves/CU vs 20) -- mild TLP loss vs 2x less to hide.
//    Same drain-barrier skeleton, direct Q->reg, stride-72 sP.

typedef unsigned short u16;
typedef unsigned int   u32;
typedef __attribute__((ext_vector_type(8))) short bf8;   // 8 x bf16 (4 VGPRs)
typedef __attribute__((ext_vector_type(4))) float f4;    // 4 x f32 accum

__device__ __forceinline__ u16 f2bf(float x) {
  u32 u = __float_as_uint(x);
  u += 0x7FFF + ((u >> 16) & 1);        // round-to-nearest-even
  return (u16)(u >> 16);
}

__device__ __forceinline__ float bf2f(u16 x) {
  return __uint_as_float(((u32)x) << 16);
}

// async global->LDS, 16B per lane. LDS dest = wave-uniform base + lane*16.
__device__ __forceinline__ void gl2lds16(const void* g, void* l) {
  __builtin_amdgcn_global_load_lds(
      (const __attribute__((address_space(1))) u32*)g,
      (__attribute__((address_space(3))) u32*)l, 16, 0, 0);
}

// ---------------- cast kernels ----------------

__global__ __launch_bounds__(256) void cast_bf16(const float* __restrict__ src,
                                                 uint4* __restrict__ dst, int n8) {
  const int i = blockIdx.x * 256 + threadIdx.x;
  if (i >= n8) return;
  const float4* s = (const float4*)src;
  const float4 a = s[2 * i], c = s[2 * i + 1];
  uint4 o;
  o.x = (u32)f2bf(a.x) | ((u32)f2bf(a.y) << 16);
  o.y = (u32)f2bf(a.z) | ((u32)f2bf(a.w) << 16);
  o.z = (u32)f2bf(c.x) | ((u32)f2bf(c.y) << 16);
  o.w = (u32)f2bf(c.z) | ((u32)f2bf(c.w) << 16);
  dst[i] = o;
}

// 4 weight matrices (1M elems each) in one launch: i>>17 selects the matrix.
__global__ __launch_bounds__(256) void cast4_bf16(
    const float* __restrict__ s0, const float* __restrict__ s1,
    const float* __restrict__ s2, const float* __restrict__ s3,
    uint4* __restrict__ d0, uint4* __restrict__ d1,
    uint4* __restrict__ d2, uint4* __restrict__ d3) {
  const int i = blockIdx.x * 256 + threadIdx.x;     // 0 .. 524287
  const int w = i >> 17, j = i & 131071;
  const float* src = (w == 0) ? s0 : (w == 1) ? s1 : (w == 2) ? s2 : s3;
  uint4* dst = (w == 0) ? d0 : (w == 1) ? d1 : (w == 2) ? d2 : d3;
  const float4* s = (const float4*)src;
  const float4 a = s[2 * j], c = s[2 * j + 1];
  uint4 o;
  o.x = (u32)f2bf(a.x) | ((u32)f2bf(a.y) << 16);
  o.y = (u32)f2bf(a.z) | ((u32)f2bf(a.w) << 16);
  o.z = (u32)f2bf(c.x) | ((u32)f2bf(c.y) << 16);
  o.w = (u32)f2bf(c.z) | ((u32)f2bf(c.w) << 16);
  dst[j] = o;
}

// bias = bf16(sp+ed), permuted so attn lane `tid` of sub-tile (b, qt, jt) reads
// its 16 values (4 rows x 4 col-groups) as one contiguous 32B chunk.
__global__ __launch_bounds__(256) void bias_perm(const float* __restrict__ sp,
                                                 const float* __restrict__ ed,
                                                 u16* __restrict__ Bp) {
  const int jt = blockIdx.x, qt = blockIdx.y, b = blockIdx.z;
  const int tid = threadIdx.x;
  const int wave = tid >> 6, quad = (tid >> 4) & 3, l16 = tid & 15;
  const int qrl = (wave << 4) + (quad << 2);
  union { u16 a[16]; uint4 v[2]; } tmp;
#pragma unroll
  for (int nb = 0; nb < 4; nb++) {
    const int col = (jt << 6) + (nb << 4) + l16;
#pragma unroll
    for (int r = 0; r < 4; r++) {
      const int row = (qt << 6) + qrl + r;
      const size_t idx = ((size_t)b << 18) + (size_t)row * 512 + col;
      tmp.a[nb * 4 + r] = f2bf(sp[idx] + ed[idx]);
    }
  }
  uint4* out = (uint4*)Bp + ((((size_t)b * 8 + qt) * 8 + jt) * 256 + tid) * 2;
  out[0] = tmp.v[0];
  out[1] = tmp.v[1];
}

// ---------------- GEMM core: C(128x128) = A(128x1024) * Bt(128x1024)^T ----------------
// A row-major [M][1024], Bt row-major [Nout][1024] (computes A @ Bt^T).
// LDS tiles are [128 rows][8 chunks of 16B], slot (r,c) holds global chunk c^(r&7).
// SWAP=true computes C^T fragments (mfma(B,A)): lane&15 -> M dim, (quad,reg) -> N
// dim, so the 4 regs of each fragment are CONSECUTIVE along N -> packed stores.

template <bool SWAP>
__device__ __forceinline__ void gemm_core(const u16* __restrict__ A,
                                          const u16* __restrict__ Bt,
                                          int m0, int n0,
                                          u16* lA, u16* lB, f4 acc[4][4]) {
  const int tid  = threadIdx.x;
  const int wave = tid >> 6;
  const int lane = tid & 63;
  const int quad = lane >> 4;
  const int l16  = lane & 15;
  const int wm   = (wave >> 1) << 6;
  const int wn   = (wave & 1) << 6;
  const int srow = tid >> 3;
  const int scol = ((tid & 7) ^ (srow & 7)) << 3;   // swizzled source chunk
  const int c0   = (quad ^ (l16 & 7)) << 3;         // swizzled read offset, kk=0

  f4 zero = {0.f, 0.f, 0.f, 0.f};
#pragma unroll
  for (int mi = 0; mi < 4; mi++)
#pragma unroll
    for (int ni = 0; ni < 4; ni++) acc[mi][ni] = zero;

  const u16* Ab = A  + (size_t)(m0 + srow) * 1024 + scol;
  const u16* Bb = Bt + (size_t)(n0 + srow) * 1024 + scol;

  for (int k0 = 0; k0 < 1024; k0 += 64) {
    __syncthreads();   // protect LDS from previous iteration's readers
#pragma unroll
    for (int i = 0; i < 4; i++) {
      gl2lds16(Ab + (size_t)(i << 5) * 1024 + k0,
               (char*)lA + (((i << 8) + (wave << 6)) << 4));
      gl2lds16(Bb + (size_t)(i << 5) * 1024 + k0,
               (char*)lB + (((i << 8) + (wave << 6)) << 4));
    }
    __syncthreads();   // drains vmcnt(0) -> tiles visible
#pragma unroll
    for (int kk = 0; kk < 64; kk += 32) {
      const int o = c0 ^ kk;
      bf8 af[4], bfr[4];
#pragma unroll
      for (int mi = 0; mi < 4; mi++)
        af[mi] = *(const bf8*)(lA + (wm + (mi << 4) + l16) * 64 + o);
#pragma unroll
      for (int ni = 0; ni < 4; ni++)
        bfr[ni] = *(const bf8*)(lB + (wn + (ni << 4) + l16) * 64 + o);
#pragma unroll
      for (int mi = 0; mi < 4; mi++)
#pragma unroll
        for (int ni = 0; ni < 4; ni++) {
          if (SWAP)
            acc[mi][ni] = __builtin_amdgcn_mfma_f32_16x16x32_bf16(
                bfr[ni], af[mi], acc[mi][ni], 0, 0, 0);
          else
            acc[mi][ni] = __builtin_amdgcn_mfma_f32_16x16x32_bf16(
                af[mi], bfr[ni], acc[mi][ni], 0, 0, 0);
        }
    }
  }
}

// ---------------- QKV projection ----------------
// XCD remap: flat bits [2:0]=m_lo [5:3]=n_tile [8:6]=m_hi [10:9]=proj.

__global__ __launch_bounds__(256) void qkv_kernel(
    const u16* __restrict__ xb, const u16* __restrict__ wq,
    const u16* __restrict__ wk, const u16* __restrict__ wv,
    u16* __restrict__ Qh, u16* __restrict__ Kh, u16* __restrict__ Vt) {
  __shared__ __align__(16) u16 lA[128 * 64];
  __shared__ __align__(16) u16 lB[128 * 64];
  const int flat = blockIdx.x + (blockIdx.y << 3) + (blockIdx.z << 9);
  const int m_tile = (flat & 7) | (((flat >> 6) & 7) << 3);
  const int n_tile = (flat >> 3) & 7;
  const int proj = flat >> 9;
  const int m0 = m_tile << 7, n0 = n_tile << 7;
  const u16* W = (proj == 0) ? wq : (proj == 1) ? wk : wv;

  const int tid = threadIdx.x, wave = tid >> 6, lane = tid & 63;
  const int quad = lane >> 4, l16 = lane & 15;
  const int wm = (wave >> 1) << 6, wn = (wave & 1) << 6;
  f4 acc[4][4];

  if (proj == 2) {
    // V: normal orientation; C rows (quad,reg) = tokens, which are the
    // contiguous dim of Vt [B,H,hd,512] -> ushort4 over 4 consecutive n.
    gemm_core<false>(xb, W, m0, n0, lA, lB, acc);
#pragma unroll
    for (int mi = 0; mi < 4; mi++) {
      const int gmb = m0 + wm + (mi << 4) + (quad << 2);
      const int b = gmb >> 9, nb = gmb & 511;
#pragma unroll
      for (int ni = 0; ni < 4; ni++) {
        const int gn = n0 + wn + (ni << 4) + l16;
        const int h = gn >> 6, hdi = gn & 63;
        ushort4 pk;
        pk.x = f2bf(acc[mi][ni][0]);
        pk.y = f2bf(acc[mi][ni][1]);
        pk.z = f2bf(acc[mi][ni][2]);
        pk.w = f2bf(acc[mi][ni][3]);
        *(ushort4*)(Vt + ((size_t)((b << 4) + h) * 64 + hdi) * 512 + nb) = pk;
      }
    }
  } else {
    // Q/K: transposed fragments; (quad,reg) = hd (contiguous in Qh/Kh),
    // lane&15 = token row -> one ushort4 per fragment.
    gemm_core<true>(xb, W, m0, n0, lA, lB, acc);
    u16* dst = (proj == 0) ? Qh : Kh;
#pragma unroll
    for (int mi = 0; mi < 4; mi++) {
      const int gm = m0 + wm + (mi << 4) + l16;      // token row
      const int b = gm >> 9, n = gm & 511;
#pragma unroll
      for (int ni = 0; ni < 4; ni++) {
        const int gn = n0 + wn + (ni << 4) + (quad << 2);  // hd dim
        const int h = gn >> 6, hdi = gn & 63;
        ushort4 pk;
        pk.x = f2bf(acc[mi][ni][0]);
        pk.y = f2bf(acc[mi][ni][1]);
        pk.z = f2bf(acc[mi][ni][2]);
        pk.w = f2bf(acc[mi][ni][3]);
        *(ushort4*)(dst + ((size_t)((b << 4) + h) * 512 + n) * 64 + hdi) = pk;
      }
    }
  }
}

// ---------------- output projection ----------------
// XCD remap: flat bits [2:0]=m_lo [5:3]=n_tile [8:6]=m_hi.
// Transposed fragments -> float4 stores (gn contiguous).

__global__ __launch_bounds__(256) void oproj_kernel(const u16* __restrict__ Ob,
                                                    const u16* __restrict__ wo,
                                                    float* __restrict__ out) {
  __shared__ __align__(16) u16 lA[128 * 64];
  __shared__ __align__(16) u16 lB[128 * 64];
  const int flat = blockIdx.x + (blockIdx.y << 3);
  const int m0 = ((flat & 7) | (((flat >> 6) & 7) << 3)) << 7;
  const int n0 = ((flat >> 3) & 7) << 7;
  f4 acc[4][4];
  gemm_core<true>(Ob, wo, m0, n0, lA, lB, acc);

  const int tid = threadIdx.x, wave = tid >> 6, lane = tid & 63;
  const int quad = lane >> 4, l16 = lane & 15;
  const int wm = (wave >> 1) << 6, wn = (wave & 1) << 6;
#pragma unroll
  for (int mi = 0; mi < 4; mi++) {
    const int gm = m0 + wm + (mi << 4) + l16;
#pragma unroll
    for (int ni = 0; ni < 4; ni++) {
      const int gn = n0 + wn + (ni << 4) + (quad << 2);
      float4 f;
      f.x = acc[mi][ni][0];
      f.y = acc[mi][ni][1];
      f.z = acc[mi][ni][2];
      f.w = acc[mi][ni][3];
      *(float4*)(out + (size_t)gm * 1024 + gn) = f;
    }
  }
}

// ---------------- fused attention: one wg per (128 q-rows, h, b) ----------------
// Q,K: [B,H,512,64] bf16.  Vt: [B,H,64,512] bf16.  512 threads, 8 waves.
// Wave w owns q-rows qh*128 + w*16 .. +15 (waves 0-3 = first 64-row qt,
// waves 4-7 = second). Per j-iter: stage K,V (ONE gl2lds each, 512 lanes x 16B
// = 8KB tile); drain; QK^T+softmax->sP; PV. Staged tile feeds 128 q-rows:
// half the staging traffic/instructions of the 64-row block.
// Q fragments direct global->reg (contiguous 16B chunks, L2-hot).
// Softmax without max-subtraction (logits bounded), one sum reduce at end.

__global__ __launch_bounds__(512, 4) void attn_kernel(
    const u16* __restrict__ Qh, const u16* __restrict__ Kh,
    const u16* __restrict__ Vt, const u16* __restrict__ Bp,
    u16* __restrict__ Ob) {
  __shared__ __align__(16) u16 sK[64 * 64];        // 8 KB
  __shared__ __align__(16) u16 sV[64 * 64];        // 8 KB, [hd][j] layout
  __shared__ __align__(16) u16 sP[8 * 16 * 72];    // 18 KB, stride-72 pad
  // grid dim3(8,4,32): x=b_lo (XCD owner: K/V+bias of 2 batches fit L2),
  // y=qh (128-row tile), z = h*2 + b_hi.
  const int b  = blockIdx.x | ((blockIdx.z & 1) << 3);
  const int qh = blockIdx.y;
  const int h  = blockIdx.z >> 1;
  const int q0 = qh << 7;
  const int tid = threadIdx.x, wave = tid >> 6, lane = tid & 63;
  const int quad = lane >> 4, l16 = lane & 15;
  const int c0  = (quad ^ (l16 & 7)) << 3;                 // swizzled read offset
  const int swb = (((tid & 7) ^ ((tid >> 3) & 7)) << 4);   // swizzled staging byte off

  const u16* Qg = Qh + ((size_t)((b << 4) + h) * 512 + q0) * 64;
  const u16* Kg = Kh + (size_t)((b << 4) + h) * 512 * 64;
  const u16* Vg = Vt + (size_t)((b << 4) + h) * 64 * 512;
  // bias sub-tile: qt = qh*2 + (wave>>2); within-qt lane id = (wave&3)*64+lane
  const int qt = (qh << 1) + (wave >> 2);
  const uint4* Bpg = (const uint4*)Bp +
      (((size_t)b * 8 + qt) * 8 * 256 + ((wave & 3) << 6) + lane) * 2;

  // Q fragments direct from global: row = wave*16 + l16 (0..127), 16B chunks.
  const bf8 aq0 = *(const bf8*)(Qg + ((wave << 4) + l16) * 64 + (quad << 3));
  const bf8 aq1 = *(const bf8*)(Qg + ((wave << 4) + l16) * 64 + 32 + (quad << 3));

  f4 o[4];
  f4 zero = {0.f, 0.f, 0.f, 0.f};
#pragma unroll
  for (int i = 0; i < 4; i++) o[i] = zero;
  float lsum[4] = {0.f, 0.f, 0.f, 0.f};

  for (int j0 = 0; j0 < 512; j0 += 64) {
    // bias chunk for this j-tile: 32B/lane, issued before the drain barrier
    const uint4 bc0 = Bpg[(j0 >> 6) * 512];
    const uint4 bc1 = Bpg[(j0 >> 6) * 512 + 1];
    const u32 bw[8] = {bc0.x, bc0.y, bc0.z, bc0.w, bc1.x, bc1.y, bc1.z, bc1.w};

    __syncthreads();   // protect LDS from previous iteration's readers
    // K tile: row = tid>>3 (0..63), chunk = tid&7 (swizzled). One inst = 8KB.
    gl2lds16((const char*)Kg + (size_t)j0 * 128 + (tid >> 3) * 128 + swb,
             (char*)sK + (wave << 10));
    gl2lds16((const char*)Vg + (size_t)(tid >> 3) * 1024 + j0 * 2 + swb,
             (char*)sV + (wave << 10));
    __syncthreads();   // drains vmcnt(0) -> K/V tiles visible

    u16* pw = sP + wave * (16 * 72);
#pragma unroll
    for (int nb = 0; nb < 4; nb++) {
      bf8 b0 = *(const bf8*)(sK + ((nb << 4) + l16) * 64 + c0);
      bf8 b1 = *(const bf8*)(sK + ((nb << 4) + l16) * 64 + (c0 ^ 32));
      f4 s = zero;
      s = __builtin_amdgcn_mfma_f32_16x16x32_bf16(aq0, b0, s, 0, 0, 0);
      s = __builtin_amdgcn_mfma_f32_16x16x32_bf16(aq1, b1, s, 0, 0, 0);
#pragma unroll
      for (int r = 0; r < 4; r++) {
        const u32 w = bw[nb * 2 + (r >> 1)];
        const float bias = bf2f((r & 1) ? (u16)(w >> 16) : (u16)(w & 0xFFFF));
        const float ev = __expf(s[r] * 0.03125f + bias);
        lsum[r] += ev;
        pw[((quad << 2) + r) * 72 + (nb << 4) + l16] = f2bf(ev);
      }
    }

    // P: C-layout -> LDS (per-wave region, in-wave ordering only)
    bf8 ap0 = *(const bf8*)(pw + l16 * 72 + (quad << 3));
    bf8 ap1 = *(const bf8*)(pw + l16 * 72 + 32 + (quad << 3));
#pragma unroll
    for (int db = 0; db < 4; db++) {
      bf8 v0 = *(const bf8*)(sV + ((db << 4) + l16) * 64 + c0);
      bf8 v1 = *(const bf8*)(sV + ((db << 4) + l16) * 64 + (c0 ^ 32));
      o[db] = __builtin_amdgcn_mfma_f32_16x16x32_bf16(ap0, v0, o[db], 0, 0, 0);
      o[db] = __builtin_amdgcn_mfma_f32_16x16x32_bf16(ap1, v1, o[db], 0, 0, 0);
    }
  }

  // epilogue: reduce row sums over the 16 l16-lanes, normalize, store
#pragma unroll
  for (int r = 0; r < 4; r++) {
    float s = lsum[r];
    s += __shfl_xor(s, 1);
    s += __shfl_xor(s, 2);
    s += __shfl_xor(s, 4);
    s += __shfl_xor(s, 8);
    const float inv = 1.f / s;
    const int gr = q0 + (wave << 4) + (quad << 2) + r;
#pragma unroll
    for (int db = 0; db < 4; db++)
      Ob[(size_t)((b << 9) + gr) * 1024 + (h << 6) + (db << 4) + l16] =
          f2bf(o[db][r] * inv);
  }
}

// ---------------- launch ----------------

extern "C" void kernel_launch(void* const* d_in, const int* in_sizes, int n_in,
                              void* d_out, int out_size, void* d_ws, size_t ws_size,
                              hipStream_t stream) {
  const float* x  = (const float*)d_in[0];
  const float* sp = (const float*)d_in[1];
  const float* ed = (const float*)d_in[2];
  const float* Wq = (const float*)d_in[3];
  const float* Wk = (const float*)d_in[4];
  const float* Wv = (const float*)d_in[5];
  const float* Wo = (const float*)d_in[6];
  float* out = (float*)d_out;

  char* w = (char*)d_ws;
  u16* xb  = (u16*)(w);                  // 16 MB  : x bf16 [8192][1024]
  u16* wqb = (u16*)(w + 16777216);       // 2 MB
  u16* wkb = (u16*)(w + 18874368);
  u16* wvb = (u16*)(w + 20971520);
  u16* wob = (u16*)(w + 23068672);
  u16* Qh  = (u16*)(w + 25165824);       // 16 MB  : [B,H,512,64]
  u16* Kh  = (u16*)(w + 41943040);       // 16 MB
  u16* Vt  = (u16*)(w + 58720256);       // 16 MB  : [B,H,64,512]
  u16* Ob  = (u16*)(w + 75497472);       // 16 MB  : [8192][1024]
  u16* Bp  = (u16*)(w + 92274688);       // 8 MB   : permuted bf16(sp+ed)

  cast_bf16<<<4096, 256, 0, stream>>>(x, (uint4*)xb, 1048576);
  cast4_bf16<<<2048, 256, 0, stream>>>(Wq, Wk, Wv, Wo,
                                       (uint4*)wqb, (uint4*)wkb,
                                       (uint4*)wvb, (uint4*)wob);
  bias_perm<<<dim3(8, 8, 16), 256, 0, stream>>>(sp, ed, Bp);

  qkv_kernel<<<dim3(8, 64, 3), 256, 0, stream>>>(xb, wqb, wkb, wvb, Qh, Kh, Vt);
  attn_kernel<<<dim3(8, 4, 32), 512, 0, stream>>>(Qh, Kh, Vt, Bp, Ob);
  oproj_kernel<<<dim3(8, 64, 1), 256, 0, stream>>>(Ob, wob, out);
}